// Round 19
// baseline (37.198 us; speedup 1.0000x reference)
//
#include <hip/hip_runtime.h>
#include <math.h>

#define HD 512
#define WD 512
#define NP 255            // patch grid = 255 x 255
#define LK 7225           // patches per kk group; 7225 = 85*85
#define BATCH 32
#define RB 85             // r's per chunk (765 ll = exactly 3 pi2-rows)
#define CH 85
#define NTHR 256
#define TENF (7 * 512)    // 3584 floats per tensor, [7][512] native rows
#define NF4  2688         // 3 tensors x 7 rows x 128 float4
#define NWG (BATCH * CH)  // 2720 (div by 8 -> clean XCD swizzle)

// Semantics (reference's flat reshape (b,9,L)->(b,L,9)):
//   l = kk*7225 + r ; (di,dj) = (kk/3, kk%3) fixed within a 9-group
//   k in 0..8: ll = 9r+k -> pixel (2*(ll/255)+di, 2*(ll%255)+dj)
//   argmin/argmax |a-c| (first-occurrence), s = c[argmin]+c[argmax]
//   broadcast to 2x2 (3x3 at edges) block of patch (l/255, l%255); row/col 511 = 0.
//
// R18 = dj-FUSION on R7's full-chunk geometry: one lane per (di,gi) cluster
// computes all 3 dj groups from ONE 19-float span per tensor (union of the
// three stride-2 reads), fetched as 10 ds_read_b64 (span base even -> 8B
// aligned). 30 b64 replace 81 b32 per cluster: 2.7x total LDS-issue cut --
// the one untried lever (R15's budget: ~10us LDS-issue). Extraction static:
// dj0,k=v[k].x; dj1,k=v[k].y; dj2,k=v[k+1].x. Wrap lanes (m=28,56 only) take
// the R7-verified scalar path (+514). Stores per dj stay gi-consecutive.
// Staging = R7 verbatim (global_load_lds, full rows). 43KB LDS, 3 blocks/CU.

typedef const __attribute__((address_space(1))) void* gp1_t;
typedef __attribute__((address_space(3))) void* lp3_t;

__global__ __launch_bounds__(NTHR) void dc_pool_kernel(
    const float* __restrict__ anchor,
    const float* __restrict__ pos,
    const float* __restrict__ neg,
    float* __restrict__ out0,
    float* __restrict__ out1)
{
    __shared__ float lds[3 * TENF];   // A | P | N ; each [7][512] native rows

    // XCD-aware swizzle (bijective: NWG % 8 == 0)
    int bid = blockIdx.x;
    int vid = (bid & 7) * (NWG / 8) + (bid >> 3);
    int chunk = vid % CH;
    int b     = vid / CH;

    const size_t plane = (size_t)HD * WD;
    const float* A = anchor + (size_t)b * plane;
    const float* P = pos    + (size_t)b * plane;
    const float* N = neg    + (size_t)b * plane;
    float* O0 = out0 + (size_t)b * plane;
    float* O1 = out1 + (size_t)b * plane;

    int tid   = threadIdx.x;
    int wbase = tid & ~63;
    int row0  = 6 * chunk;            // first staged image row (max 510)

    // ---- stage 7 full rows x 3 tensors = 2688 x 16B via global_load_lds ----
    // (R7 verbatim; u -> tensor u/896, row (u%896)/128, col4 u%128)
    #pragma unroll
    for (int J = 0; J < 11; ++J) {
        int u = J * NTHR + tid;
        if (u < NF4) {                // wave-uniform (J=10: waves 0-1 only)
            int tensor = u / 896;
            int rem    = u - tensor * 896;
            int rr     = rem >> 7;
            int col4   = rem & 127;
            const float* g = (tensor == 0 ? A : (tensor == 1 ? P : N))
                             + (size_t)(row0 + rr) * WD + col4 * 4;
            float* l = &lds[(size_t)(J * NTHR + wbase) * 4];
            __builtin_amdgcn_global_load_lds((gp1_t)(const void*)g,
                                             (lp3_t)(void*)l, 16, 0, 0);
        }
    }
    __syncthreads();   // drains vmcnt; one-shot block

    // ---- compute: one (di,gi) cluster per lane; all 3 dj from one span ----
    if (tid < 255) {
        int di  = tid / 85;           // 0..2
        int gi  = tid - di * 85;      // 0..84 ( = m )
        int loc = 9 * gi;
        int j   = loc / NP;           // 0..2
        int pj2 = loc - NP * j;
        int r   = chunk * RB + gi;
        int sB  = (2 * j + di) * 512 + 2 * pj2;   // even -> 8B-aligned span base
        int wrapk = NP - pj2;         // <9 only for gi=28 (j=0) and gi=56 (j=1)

        float s0v[3], s1v[3];

        if (wrapk >= 9) {
            // span path: 10 float2 per tensor (19 floats cover dj+2k, 0..18)
            float2 va[10], vp[10], vn[10];
            #pragma unroll
            for (int i = 0; i < 10; ++i) {
                va[i] = *reinterpret_cast<const float2*>(&lds[sB + 2 * i]);
                vp[i] = *reinterpret_cast<const float2*>(&lds[TENF + sB + 2 * i]);
                vn[i] = *reinterpret_cast<const float2*>(&lds[2 * TENF + sB + 2 * i]);
            }
            #pragma unroll
            for (int dj = 0; dj < 3; ++dj) {
                float minvP = 0.f, maxvP = 0.f, mindP = INFINITY, maxdP = -INFINITY;
                float minvN = 0.f, maxvN = 0.f, mindN = INFINITY, maxdN = -INFINITY;
                #pragma unroll
                for (int k = 0; k < 9; ++k) {
                    float a = (dj == 0) ? va[k].x : (dj == 1) ? va[k].y : va[k + 1].x;
                    float p = (dj == 0) ? vp[k].x : (dj == 1) ? vp[k].y : vp[k + 1].x;
                    float n = (dj == 0) ? vn[k].x : (dj == 1) ? vn[k].y : vn[k + 1].x;
                    float dp = fabsf(a - p);
                    float dn = fabsf(a - n);
                    if (dp < mindP) { mindP = dp; minvP = p; }   // first-occurrence argmin
                    if (dp > maxdP) { maxdP = dp; maxvP = p; }   // first-occurrence argmax
                    if (dn < mindN) { mindN = dn; minvN = n; }
                    if (dn > maxdN) { maxdN = dn; maxvN = n; }
                }
                s0v[dj] = minvP + maxvP;
                s1v[dj] = minvN + maxvN;
            }
        } else {
            // scalar fallback (2 lanes/block): R7-verified wrap formula (+514)
            #pragma unroll
            for (int dj = 0; dj < 3; ++dj) {
                float minvP = 0.f, maxvP = 0.f, mindP = INFINITY, maxdP = -INFINITY;
                float minvN = 0.f, maxvN = 0.f, mindN = INFINITY, maxdN = -INFINITY;
                #pragma unroll
                for (int k = 0; k < 9; ++k) {
                    int lo = sB + dj + 2 * k + ((k >= wrapk) ? 514 : 0);
                    float a = lds[lo];
                    float p = lds[TENF + lo];
                    float n = lds[2 * TENF + lo];
                    float dp = fabsf(a - p);
                    float dn = fabsf(a - n);
                    if (dp < mindP) { mindP = dp; minvP = p; }
                    if (dp > maxdP) { maxdP = dp; maxvP = p; }
                    if (dn < mindN) { mindN = dn; minvN = n; }
                    if (dn > maxdN) { maxdN = dn; maxvN = n; }
                }
                s0v[dj] = minvP + maxvP;
                s1v[dj] = minvN + maxvN;
            }
        }

        // ---- scatter: per dj, consecutive gi -> consecutive float2 ----
        #pragma unroll
        for (int dj = 0; dj < 3; ++dj) {
            float s0 = s0v[dj];
            float s1 = s1v[dj];
            int l   = (3 * di + dj) * LK + r;
            int piy = l / NP;
            int pjx = l - piy * NP;
            int y0  = 2 * piy;
            int x0  = 2 * pjx;
            bool right  = (pjx == NP - 1);
            bool bottom = (piy == NP - 1);
            int ny = bottom ? 3 : 2;

            for (int yy = 0; yy < ny; ++yy) {
                float* p0 = O0 + (size_t)(y0 + yy) * WD + x0;
                float* p1 = O1 + (size_t)(y0 + yy) * WD + x0;
                if (right) {    // cols 508,509,510 = s ; col 511 = 0
                    *reinterpret_cast<float4*>(p0) = make_float4(s0, s0, s0, 0.f);
                    *reinterpret_cast<float4*>(p1) = make_float4(s1, s1, s1, 0.f);
                } else {
                    *reinterpret_cast<float2*>(p0) = make_float2(s0, s0);
                    *reinterpret_cast<float2*>(p1) = make_float2(s1, s1);
                }
            }
            if (bottom) {       // row 511 = 0
                float* p0 = O0 + (size_t)(HD - 1) * WD + x0;
                float* p1 = O1 + (size_t)(HD - 1) * WD + x0;
                if (right) {
                    *reinterpret_cast<float4*>(p0) = make_float4(0.f, 0.f, 0.f, 0.f);
                    *reinterpret_cast<float4*>(p1) = make_float4(0.f, 0.f, 0.f, 0.f);
                } else {
                    *reinterpret_cast<float2*>(p0) = make_float2(0.f, 0.f);
                    *reinterpret_cast<float2*>(p1) = make_float2(0.f, 0.f);
                }
            }
        }
    }
}

extern "C" void kernel_launch(void* const* d_in, const int* in_sizes, int n_in,
                              void* d_out, int out_size, void* d_ws, size_t ws_size,
                              hipStream_t stream) {
    const float* anchor = (const float*)d_in[0];
    const float* pos    = (const float*)d_in[1];
    const float* neg    = (const float*)d_in[2];
    float* out0 = (float*)d_out;
    float* out1 = out0 + (size_t)BATCH * HD * WD;

    dc_pool_kernel<<<NWG, NTHR, 0, stream>>>(anchor, pos, neg, out0, out1);
}

// Round 20
// 34.890 us; speedup vs baseline: 1.0661x; 1.0661x over previous
//
#include <hip/hip_runtime.h>
#include <math.h>

#define HD 512
#define WD 512
#define NP 255            // patch grid = 255 x 255
#define LK 7225           // patches per kk group; 7225 = 85*85
#define BATCH 32
#define RB 85             // r's per chunk (765 ll = exactly 3 pi2-rows)
#define CH 85
#define NTHR 448          // 7 waves; single compute pass (387/378 groups)
#define TCOLS 288         // native row layout; h=0 cols [0,288); h=1 [240,512)+strip
#define TENF (7 * TCOLS)  // 2016 floats per tensor (24192 B total LDS)
#define NF4  1512         // 3 tensors x 7 rows x 72 float4
#define NWG (BATCH * CH * 2)   // 5440 (div by 8 -> clean XCD swizzle)

// Semantics (reference's flat reshape (b,9,L)->(b,L,9)):
//   l = kk*7225 + r ; (di,dj) = (kk/3, kk%3) fixed within a 9-group
//   k in 0..8: ll = 9r+k -> pixel (2*(ll/255)+di, 2*(ll%255)+dj)
//   argmin/argmax |a-c| (first-occurrence), s = c[argmin]+c[argmax]
//   broadcast to 2x2 (3x3 at edges) block of patch (l/255, l%255); row/col 511 = 0.
//
// FINAL (R15, twice-reproduced 35.07-35.09 us, absmax 0):
//  - R8 half-chunk geometry + contiguous 7-row fetch + XCD swizzle (FETCH 49MB)
//  - global_load_lds direct staging, NATIVE [7][288] layout
//  - single-pass kk-major compute: 448 thr, one (kk,gi) group per lane;
//    stores gi-consecutive = coalesced float2
//  - wrap bump +578: pj2>=247 reads strip entries [272,288) two rows down
// Falsified levers (each improved in isolation, none beat 35.07):
//  LDS-issue count & conflicts (R18: 2.7x fewer reads, 4x fewer conflicts ->
//  37.2), occupancy (R6/R12/R16: up to 60% -> neutral/worse), deeper
//  pipelining (R4/R5), parity bank layouts (R11/R13/R14), quarter blocks (R9).
// Residual vs 18.4us HBM floor = distributed stage-drain + compute + store
// latency, all pipes 25-45%.

typedef const __attribute__((address_space(1))) void* gp1_t;
typedef __attribute__((address_space(3))) void* lp3_t;

__global__ __launch_bounds__(NTHR) void dc_pool_kernel(
    const float* __restrict__ anchor,
    const float* __restrict__ pos,
    const float* __restrict__ neg,
    float* __restrict__ out0,
    float* __restrict__ out1)
{
    __shared__ float lds[3 * TENF];   // A | P | N ; each [7][288] native cols

    // XCD-aware swizzle (bijective: NWG % 8 == 0); halves of a chunk adjacent.
    int bid = blockIdx.x;
    int vid = (bid & 7) * (NWG / 8) + (bid >> 3);
    int h     = vid & 1;
    int rest  = vid >> 1;
    int chunk = rest % CH;
    int b     = rest / CH;

    const size_t plane = (size_t)HD * WD;
    const float* A = anchor + (size_t)b * plane;
    const float* P = pos    + (size_t)b * plane;
    const float* N = neg    + (size_t)b * plane;
    float* O0 = out0 + (size_t)b * plane;
    float* O1 = out1 + (size_t)b * plane;

    int tid   = threadIdx.x;
    int wbase = tid & ~63;
    int row0  = 6 * chunk;            // first staged image row (max 510)

    // ---- stage 7 rows x 72 f4 x 3 tensors = 1512 x 16B via global_load_lds ----
    // u -> tensor u/504, row (u%504)/72, c4 (u%504)%72 ; LDS dst linear in u.
    // h=0: gcol4 = c4 (cols [0,288)).
    // h=1: c4<68 -> gcol4 = 60+c4 (cols [240,512)); c4>=68 -> strip cols [0,16)
    //      at entries [272,288).
    #pragma unroll
    for (int J = 0; J < 4; ++J) {
        int u = J * NTHR + tid;
        if (u < NF4) {
            int t   = u / 504;
            int rem = u - t * 504;
            int rr  = rem / 72;
            int c4  = rem - rr * 72;
            int g4  = (h == 0) ? c4 : (c4 < 68 ? 60 + c4 : c4 - 68);
            const float* g = (t == 0 ? A : (t == 1 ? P : N))
                             + (size_t)(row0 + rr) * WD + g4 * 4;
            float* l = &lds[(size_t)(J * NTHR + wbase) * 4];
            __builtin_amdgcn_global_load_lds((gp1_t)(const void*)g,
                                             (lp3_t)(void*)l, 16, 0, 0);
        }
    }
    __syncthreads();   // drains vmcnt; one-shot block

    // ---- compute: one (kk, gi) group per lane; lane = kk*NGM + gi (1 pass) ----
    int NGM   = 43 - h;               // m's in this half
    int total = 9 * NGM;              // 387 / 378  (<= NTHR)
    if (tid < total) {
        int kk = tid / NGM;
        int gi = tid - kk * NGM;
        int di = kk / 3;
        int dj = kk - 3 * di;

        int j, m;
        if (!h) { j = (gi < 15) ? 0 : ((gi < 29) ? 1 : 2);
                  m = gi + ((gi < 15) ? 0 : ((gi < 29) ? 14 : 28)); }
        else    { j = (gi < 14) ? 0 : ((gi < 28) ? 1 : 2);
                  m = gi + ((gi < 14) ? 15 : ((gi < 28) ? 29 : 43)); }
        int pj2 = 9 * m - 255 * j;    // h=0: [0,126] ; h=1: [129,252]
        int r   = chunk * RB + m;
        int rr  = 2 * j + di;

        int base0 = rr * TCOLS + 2 * pj2 + dj - (h ? 240 : 0);
        int wrapk = NP - pj2;         // <=8 only in h=1 (pj2>=247)

        float minvP = 0.f, maxvP = 0.f, mindP = INFINITY, maxdP = -INFINITY;
        float minvN = 0.f, maxvN = 0.f, mindN = INFINITY, maxdN = -INFINITY;
        #pragma unroll
        for (int k = 0; k < 9; ++k) {
            int lo = base0 + 2 * k + ((k >= wrapk) ? 578 : 0);  // wrap: +2 rows, strip
            float a = lds[lo];
            float p = lds[TENF + lo];
            float n = lds[2 * TENF + lo];
            float dp = fabsf(a - p);
            float dn = fabsf(a - n);
            if (dp < mindP) { mindP = dp; minvP = p; }   // first-occurrence argmin
            if (dp > maxdP) { maxdP = dp; maxvP = p; }   // first-occurrence argmax
            if (dn < mindN) { mindN = dn; minvN = n; }
            if (dn > maxdN) { maxdN = dn; maxvN = n; }
        }
        float s0 = minvP + maxvP;
        float s1 = minvN + maxvN;

        // ---- scatter to output (consecutive gi -> consecutive float2) ----
        int l   = kk * LK + r;
        int piy = l / NP;
        int pjx = l - piy * NP;
        int y0  = 2 * piy;
        int x0  = 2 * pjx;
        bool right  = (pjx == NP - 1);
        bool bottom = (piy == NP - 1);
        int ny = bottom ? 3 : 2;

        for (int yy = 0; yy < ny; ++yy) {
            float* p0 = O0 + (size_t)(y0 + yy) * WD + x0;
            float* p1 = O1 + (size_t)(y0 + yy) * WD + x0;
            if (right) {    // cols 508,509,510 = s ; col 511 = 0
                *reinterpret_cast<float4*>(p0) = make_float4(s0, s0, s0, 0.f);
                *reinterpret_cast<float4*>(p1) = make_float4(s1, s1, s1, 0.f);
            } else {
                *reinterpret_cast<float2*>(p0) = make_float2(s0, s0);
                *reinterpret_cast<float2*>(p1) = make_float2(s1, s1);
            }
        }
        if (bottom) {       // row 511 = 0
            float* p0 = O0 + (size_t)(HD - 1) * WD + x0;
            float* p1 = O1 + (size_t)(HD - 1) * WD + x0;
            if (right) {
                *reinterpret_cast<float4*>(p0) = make_float4(0.f, 0.f, 0.f, 0.f);
                *reinterpret_cast<float4*>(p1) = make_float4(0.f, 0.f, 0.f, 0.f);
            } else {
                *reinterpret_cast<float2*>(p0) = make_float2(0.f, 0.f);
                *reinterpret_cast<float2*>(p1) = make_float2(0.f, 0.f);
            }
        }
    }
}

extern "C" void kernel_launch(void* const* d_in, const int* in_sizes, int n_in,
                              void* d_out, int out_size, void* d_ws, size_t ws_size,
                              hipStream_t stream) {
    const float* anchor = (const float*)d_in[0];
    const float* pos    = (const float*)d_in[1];
    const float* neg    = (const float*)d_in[2];
    float* out0 = (float*)d_out;
    float* out1 = out0 + (size_t)BATCH * HD * WD;

    dc_pool_kernel<<<NWG, NTHR, 0, stream>>>(anchor, pos, neg, out0, out1);
}